// Round 22
// baseline (36.041 us; speedup 1.0000x reference)
//
#include <hip/hip_runtime.h>

// DivEncLayer via MFMA — WAVE-SELF-CONTAINED: zero in-loop barriers.
// Per (b,q): h = elu(x[b,q*8:+8]@W1[q] + b1[q]); LN(h); out = h@W2[q]+b2[q].
// B=16384, Q=128, S=8, U=32.
//
// r16-r21 synthesis: per-SIMD issue demand ~10us, wall 27.7us; every overlap
// scheme inside the barrier-locked 4-wave block was null. Residual suspect:
// block barriers convoy all waves every 64 rows. This round: each wave owns
// 4 q's x its own 128-row strip, stages its own fp32 panel via global_load_lds
// (linear dest + source-swizzled chunks — r20-validated), 2-panel ring,
// same-wave ordering only (explicit vmcnt(0) before reads; next panel's
// gloads issued AFTER all ds_reads so they fly through the VALU phase).
// NO barriers until one final __syncthreads before the r17 gather/store.
//
// v_mfma_f32_32x32x16_bf16 mapping (validated r2-r11):
//   A: lane l, reg j -> A[l&31][j+8*(l>>5)]  B: lane l, reg j -> B[j+8*(l>>5)][l&31]
//   D: lane l, reg r -> row u=(r&3)+8*(r>>2)+4*(l>>5), col b=l&31
// Packed A-frag: lanes<32 = bf16(W1^T) (k<8), lanes>=32 = bf16(W1-hi) (k>=8).
// B duplicates rows across halves. D = (whi+wlo)*xhi + 0; b1 added in ELU
// from wave-private LDS param pairs (r5-validated). LN+Dense2 folded:
//   out = rsqrt(var+eps)*(dot(e,g2) - mu*G) + C.
// Panel swizzle (r20-validated): stage source chunk (l&7)^(l>>3) -> row r
// chunk c at slot c^(r&7); read bank spread 8x4B, 2-way max per 16-lane group.
// Block = 4 independent waves; wave w rows [bx*512+w*128, +128), 4 iters x 32.
// Grid (32,32) = 1024 blocks. lout gather -> float4 stores (write-exact).

typedef __attribute__((ext_vector_type(8))) short short8;    // 8 bf16
typedef __attribute__((ext_vector_type(16))) float f32x16;

__device__ __forceinline__ short fbits(__bf16 b) { return __builtin_bit_cast(short, b); }

__device__ __forceinline__ float elu1(float v) {
    return v > 0.f ? v : __expf(v) - 1.f;
}

__global__ __launch_bounds__(256, 3) void divenc_wi(
    const float* __restrict__ x,      // (16384, 1024)
    const float* __restrict__ W1,     // (128, 8, 32)
    const float* __restrict__ b1,     // (128, 32)
    const float* __restrict__ gamma,  // (128, 32)
    const float* __restrict__ beta,   // (128, 32)
    const float* __restrict__ W2,     // (128, 32)
    const float* __restrict__ b2,     // (128,)
    float* __restrict__ out)          // (16384, 128)
{
    __shared__ float xpan[4][2][32 * 32];   // [wave][ring][row*32], 32 KB
    __shared__ float pl[4][4][32][2];       // [wave][q][u][{b1,g2}], 4 KB
    __shared__ float lout[512 * 5];         // results, padded stride 5, 10 KB

    const int tid  = threadIdx.x;
    const int w    = tid >> 6;
    const int ln   = tid & 63;
    const int u    = ln & 31;
    const int half = ln >> 5;
    const int qt   = blockIdx.y;            // 0..31
    const int bx   = blockIdx.x;            // 0..31
    const int band = bx * 512;
    const int wrow = band + w * 128;        // this wave's 128-row strip

    // staging source swizzle (r20): lane l covers row (l>>3), chunk (l&7)^(l>>3)
    const int rsub = ln >> 3;               // 0..7
    const int chk  = (ln & 7) ^ rsub;
    const float* gsrc = x + qt * 32 + chk * 4;

    // ---- A-frags (4 q): lanes<32 = whi (k<8), lanes>=32 = wlo (k>=8) ----
    short8 wfrag[4];
    float Gv[4], Cv[4];
    #pragma unroll
    for (int qq = 0; qq < 4; ++qq) {
        const int q = qt * 4 + qq;
        #pragma unroll
        for (int j = 0; j < 8; ++j) {
            float f  = W1[q * 256 + j * 32 + u];
            __bf16 h = (__bf16)f;
            wfrag[qq][j] = half ? fbits((__bf16)(f - (float)h)) : fbits(h);
        }
        float w2 = W2[q * 32 + u];
        float g2 = gamma[q * 32 + u] * w2;
        if (half == 0) {
            pl[w][qq][u][0] = b1[q * 32 + u];
            pl[w][qq][u][1] = g2;
        }
        float gs = g2, cs = beta[q * 32 + u] * w2;
        #pragma unroll
        for (int m = 1; m < 32; m <<= 1) {   // halves dup u -> 5 steps suffice
            gs += __shfl_xor(gs, m);
            cs += __shfl_xor(cs, m);
        }
        Gv[qq] = gs;
        Cv[qq] = cs + b2[q];
    }

    // ---- prologue: issue panel 0's gloads (4 instrs, 8 rows each) ----
    #pragma unroll
    for (int i = 0; i < 4; ++i) {
        const float* ga = gsrc + (size_t)(wrow + i * 8 + rsub) * 1024;
        __builtin_amdgcn_global_load_lds(ga, &xpan[w][0][i * 256], 16, 0, 0);
    }

    #pragma unroll 1
    for (int it = 0; it < 4; ++it) {
        const int cur = it & 1;
        const int b0  = it * 32;             // row offset within strip

        // wait this panel's gloads (issued last iter; had a full VALU phase)
        asm volatile("s_waitcnt vmcnt(0)" ::: "memory");

        // ---- read ALL frags first (so next gloads can fly over compute) ----
        const float* pan = &xpan[w][cur][0];
        float4 f0[4], f1[4];
        #pragma unroll
        for (int qq = 0; qq < 4; ++qq) {
            const int s0 = 4 * ((2 * qq)     ^ (u & 7));
            const int s1 = 4 * ((2 * qq + 1) ^ (u & 7));
            f0[qq] = *(const float4*)&pan[u * 32 + s0];
            f1[qq] = *(const float4*)&pan[u * 32 + s1];
        }

        // ---- issue next panel's gloads (stay in flight through compute) ----
        if (it < 3) {
            #pragma unroll
            for (int i = 0; i < 4; ++i) {
                const float* ga = gsrc + (size_t)(wrow + b0 + 32 + i * 8 + rsub) * 1024;
                __builtin_amdgcn_global_load_lds(ga, &xpan[w][cur ^ 1][i * 256], 16, 0, 0);
            }
        }

        // ---- 4 independent MFMA+finish chains ----
        #pragma unroll
        for (int qq = 0; qq < 4; ++qq) {
            short8 xf;
            xf[0] = fbits((__bf16)f0[qq].x); xf[1] = fbits((__bf16)f0[qq].y);
            xf[2] = fbits((__bf16)f0[qq].z); xf[3] = fbits((__bf16)f0[qq].w);
            xf[4] = fbits((__bf16)f1[qq].x); xf[5] = fbits((__bf16)f1[qq].y);
            xf[6] = fbits((__bf16)f1[qq].z); xf[7] = fbits((__bf16)f1[qq].w);

            f32x16 z = {};
            f32x16 acc = __builtin_amdgcn_mfma_f32_32x32x16_bf16(wfrag[qq], xf, z, 0, 0, 0);

            float sum = 0.f, ss = 0.f, dot = 0.f;
            #pragma unroll
            for (int c = 0; c < 4; ++c) {
                const int ub = 4 * half + 8 * c;          // r=4c+j -> u=ub+j
                float4 bg0 = *(const float4*)&pl[w][qq][ub][0];
                float4 bg1 = *(const float4*)&pl[w][qq][ub + 2][0];
                float e0 = elu1(acc[4 * c + 0] + bg0.x);
                float e1 = elu1(acc[4 * c + 1] + bg0.z);
                float e2 = elu1(acc[4 * c + 2] + bg1.x);
                float e3 = elu1(acc[4 * c + 3] + bg1.z);
                sum += (e0 + e1) + (e2 + e3);
                ss  = fmaf(e0, e0, fmaf(e1, e1, fmaf(e2, e2, fmaf(e3, e3, ss))));
                dot = fmaf(e0, bg0.y, fmaf(e1, bg0.w, fmaf(e2, bg1.y, fmaf(e3, bg1.w, dot))));
            }
            sum += __shfl_xor(sum, 32);
            ss  += __shfl_xor(ss, 32);
            dot += __shfl_xor(dot, 32);
            float mu  = sum * 0.03125f;
            float var = fmaf(-mu, mu, ss * 0.03125f);
            float inv = rsqrtf(var + 1e-3f);
            float res = fmaf(inv, fmaf(-mu, Gv[qq], dot), Cv[qq]);

            if (half == 0)
                lout[(w * 128 + b0 + u) * 5 + qq] = res;   // wave-private rows
        }
    }

    __syncthreads();   // the ONLY block barrier: lout visibility

    // ---- gather/store: 512 rows, 2 per thread, float4 each (write-exact) ----
    {
        const int r0 = tid;
        const int r1 = tid + 256;
        float4 o0, o1;
        o0.x = lout[r0 * 5 + 0]; o0.y = lout[r0 * 5 + 1];
        o0.z = lout[r0 * 5 + 2]; o0.w = lout[r0 * 5 + 3];
        o1.x = lout[r1 * 5 + 0]; o1.y = lout[r1 * 5 + 1];
        o1.z = lout[r1 * 5 + 2]; o1.w = lout[r1 * 5 + 3];
        *(float4*)(out + (size_t)(band + r0) * 128 + qt * 4) = o0;
        *(float4*)(out + (size_t)(band + r1) * 128 + qt * 4) = o1;
    }
}

extern "C" void kernel_launch(void* const* d_in, const int* in_sizes, int n_in,
                              void* d_out, int out_size, void* d_ws, size_t ws_size,
                              hipStream_t stream) {
    const float* x     = (const float*)d_in[0];
    const float* W1    = (const float*)d_in[1];
    const float* b1    = (const float*)d_in[2];
    const float* gamma = (const float*)d_in[3];
    const float* beta  = (const float*)d_in[4];
    const float* W2    = (const float*)d_in[5];
    const float* b2    = (const float*)d_in[6];
    float* out = (float*)d_out;

    dim3 grid(32, 32);   // (512-row bands, q-tiles of 4)
    divenc_wi<<<grid, 256, 0, stream>>>(x, W1, b1, gamma, beta, W2, b2, out);
}

// Round 23
// 27.782 us; speedup vs baseline: 1.2973x; 1.2973x over previous
//
#include <hip/hip_runtime.h>

// DivEncLayer via MFMA — r17 (best, 27.68us) + CONVOY-BREAKING START STAGGER.
// Per (b,q): h = elu(x[b,q*8:+8]@W1[q] + b1[q]); LN(h); out = h@W2[q]+b2[q].
// B=16384, Q=128, S=8, U=32.
//
// r16-r22 synthesis: phase costs additive; every intra-block overlap scheme
// null. Root cause hypothesis: with 1024 blocks / 256 CUs, the 4 co-resident
// blocks per CU (linear IDs i, i+256, i+512, i+768) all start at t=0 running
// identical code -> ALL waves on a CU stage together, compute together
// (macro-convoy; the shared memory system re-syncs any drift). Fix: delay
// generation g = (linearId>>8)&3 by g*0.4us (s_sleep(15) each) BEFORE any
// loads. Generation g's staging bursts then land inside g-1's compute
// windows for all 8 iterations. Kernel body = r17 byte-identical.
//
// v_mfma_f32_32x32x16_bf16 mapping (validated r2-r11):
//   A: lane l, reg j -> A[l&31][j+8*(l>>5)]  B: lane l, reg j -> B[j+8*(l>>5)][l&31]
//   D: lane l, reg r -> row u=(r&3)+8*(r>>2)+4*(l>>5), col b=l&31
// Packed A-frag: lanes<32 = bf16(W1^T) (k<8), lanes>=32 = bf16(W1-hi) (k>=8).
// B-frag: staged bf16 panel row u (halves dup) -> one ds_read_b128.
// D = (whi+wlo)*xhi + b1 (C-in fp32). LN+Dense2 folded:
//   out = rsqrt(var+eps)*(dot(e,g2) - mu*G) + C.
// Staging: 3-deep ring, loads 2 iters ahead, lgkmcnt-only barriers (global
// loads stay in flight across barriers). Block = 4 waves = q-tile;
// 8 iters x 64 rows = 512-row band; grid (32,32). lout gather, float4 stores.

typedef __attribute__((ext_vector_type(8))) short short8;    // 8 bf16
typedef __attribute__((ext_vector_type(16))) float f32x16;

#define XS_STRIDE 40   // shorts per staged row (80 B): b128-aligned, 0-conflict

__device__ __forceinline__ short fbits(__bf16 b) { return __builtin_bit_cast(short, b); }

__device__ __forceinline__ float elu1(float v) {
    return v > 0.f ? v : __expf(v) - 1.f;
}

__device__ __forceinline__ short4 cvt4(float4 v) {
    short4 r;
    r.x = fbits((__bf16)v.x); r.y = fbits((__bf16)v.y);
    r.z = fbits((__bf16)v.z); r.w = fbits((__bf16)v.w);
    return r;
}

// barrier WITHOUT vmcnt drain: DS visibility only; global loads stay in flight
__device__ __forceinline__ void barrier_ds_only() {
    asm volatile("s_waitcnt lgkmcnt(0)" ::: "memory");
    __builtin_amdgcn_s_barrier();
}

__global__ __launch_bounds__(256, 4) void divenc_mfma(
    const float* __restrict__ x,      // (16384, 1024)
    const float* __restrict__ W1,     // (128, 8, 32)
    const float* __restrict__ b1,     // (128, 32)
    const float* __restrict__ gamma,  // (128, 32)
    const float* __restrict__ beta,   // (128, 32)
    const float* __restrict__ W2,     // (128, 32)
    const float* __restrict__ b2,     // (128,)
    float* __restrict__ out)          // (16384, 128)
{
    __shared__ short xs[3][64 * XS_STRIDE];   // 3-deep staged bf16 panels (15 KB)
    __shared__ float lout[512 * 5];           // results, padded stride 5 (10 KB)

    // ---- convoy-breaking stagger: generation g sleeps g*~0.4us ----
    {
        const int lin = blockIdx.x + blockIdx.y * gridDim.x;   // 0..1023
        const int gen = (lin >> 8) & 3;   // co-resident generation on a CU
        #pragma unroll 1
        for (int i = 0; i < gen; ++i) __builtin_amdgcn_s_sleep(15);   // ~960 cyc
    }

    const int tid  = threadIdx.x;
    const int w    = tid >> 6;
    const int ln   = tid & 63;
    const int u    = ln & 31;
    const int half = ln >> 5;
    const int qt   = blockIdx.y;      // 0..31
    const int q    = qt * 4 + w;
    const int bx   = blockIdx.x;      // 0..31; band = rows bx*512..+511
    const int band = bx * 512;

    // staging role: 8 threads cover one 128B row; thread t does rows t>>3, +32
    const int srow0 = tid >> 3;
    const int srow1 = srow0 + 32;
    const int schk  = tid & 7;
    const float* xpan = x + qt * 32 + schk * 4;

    // ---- A-frag: lanes<32 = whi (k=0..7), lanes>=32 = wlo (k=8..15) ----
    short8 wfrag;
    #pragma unroll
    for (int j = 0; j < 8; ++j) {
        float f  = W1[q * 256 + j * 32 + u];
        __bf16 h = (__bf16)f;
        wfrag[j] = half ? fbits((__bf16)(f - (float)h)) : fbits(h);
    }

    // ---- params: biasr (MFMA C-in) + g2r in regs, vector loads ----
    f32x16 biasr, g2r;
    float G, C;
    {
        float gs = 0.f, cs = 0.f;
        #pragma unroll
        for (int c = 0; c < 4; ++c) {
            const int ub = q * 32 + 4 * half + 8 * c;
            float4 b1v = *(const float4*)&b1[ub];
            float4 gav = *(const float4*)&gamma[ub];
            float4 w2v = *(const float4*)&W2[ub];
            float4 bev = *(const float4*)&beta[ub];
            #pragma unroll
            for (int j = 0; j < 4; ++j) {
                float g2 = ((const float*)&gav)[j] * ((const float*)&w2v)[j];
                biasr[4 * c + j] = ((const float*)&b1v)[j];
                g2r[4 * c + j]   = g2;
                gs += g2;
                cs += ((const float*)&bev)[j] * ((const float*)&w2v)[j];
            }
        }
        gs += __shfl_xor(gs, 32);   // halves hold complementary u-sets
        cs += __shfl_xor(cs, 32);
        G = gs;
        C = cs + b2[q];
    }

    // ---- prologue: stage panel 0; issue panel 1's loads (stay in flight) ----
    {
        float4 g0 = *(const float4*)(xpan + (size_t)(band + srow0) * 1024);
        float4 g1 = *(const float4*)(xpan + (size_t)(band + srow1) * 1024);
        *(short4*)&xs[0][srow0 * XS_STRIDE + schk * 4] = cvt4(g0);
        *(short4*)&xs[0][srow1 * XS_STRIDE + schk * 4] = cvt4(g1);
    }
    float4 p0 = *(const float4*)(xpan + (size_t)(band + 64 + srow0) * 1024);
    float4 p1 = *(const float4*)(xpan + (size_t)(band + 64 + srow1) * 1024);
    barrier_ds_only();

    #pragma unroll 1
    for (int it = 0; it < 8; ++it) {
        const int cur = it % 3;
        const int nxt = (it + 1) % 3;
        const int b0  = it * 64;        // row offset within band

        // issue loads for panel it+2 (2 iterations ahead; stay in flight)
        float4 f0, f1;
        if (it < 6) {
            f0 = *(const float4*)(xpan + (size_t)(band + b0 + 128 + srow0) * 1024);
            f1 = *(const float4*)(xpan + (size_t)(band + b0 + 128 + srow1) * 1024);
        }

        // ---- compute on panel cur (bit-identical to r11/r17) ----
        short8 xa = *(const short8*)&xs[cur][u * XS_STRIDE + w * 8];
        short8 xb = *(const short8*)&xs[cur][(u + 32) * XS_STRIDE + w * 8];

        f32x16 accA = __builtin_amdgcn_mfma_f32_32x32x16_bf16(wfrag, xa, biasr, 0, 0, 0);
        f32x16 accB = __builtin_amdgcn_mfma_f32_32x32x16_bf16(wfrag, xb, biasr, 0, 0, 0);

        {
            float sum = 0.f, ss = 0.f, dot = 0.f;
            #pragma unroll
            for (int r = 0; r < 16; ++r) {
                float e = elu1(accA[r]);
                sum += e;
                ss  = fmaf(e, e, ss);
                dot = fmaf(e, g2r[r], dot);
            }
            sum += __shfl_xor(sum, 32);
            ss  += __shfl_xor(ss, 32);
            dot += __shfl_xor(dot, 32);
            float mu  = sum * 0.03125f;
            float var = fmaf(-mu, mu, ss * 0.03125f);
            float inv = rsqrtf(var + 1e-3f);
            float res = fmaf(inv, fmaf(-mu, G, dot), C);
            if (half == 0) lout[(b0 + u) * 5 + w] = res;
        }
        {
            float sum = 0.f, ss = 0.f, dot = 0.f;
            #pragma unroll
            for (int r = 0; r < 16; ++r) {
                float e = elu1(accB[r]);
                sum += e;
                ss  = fmaf(e, e, ss);
                dot = fmaf(e, g2r[r], dot);
            }
            sum += __shfl_xor(sum, 32);
            ss  += __shfl_xor(ss, 32);
            dot += __shfl_xor(dot, 32);
            float mu  = sum * 0.03125f;
            float var = fmaf(-mu, mu, ss * 0.03125f);
            float inv = rsqrtf(var + 1e-3f);
            float res = fmaf(inv, fmaf(-mu, G, dot), C);
            if (half == 0) lout[(b0 + 32 + u) * 5 + w] = res;
        }

        // ---- write panel it+1 from pending regs (vmcnt counted, not drained) ----
        if (it < 7) {
            *(short4*)&xs[nxt][srow0 * XS_STRIDE + schk * 4] = cvt4(p0);
            *(short4*)&xs[nxt][srow1 * XS_STRIDE + schk * 4] = cvt4(p1);
            barrier_ds_only();   // DS visibility only; vmcnt NOT drained
        }

        p0 = f0;
        p1 = f1;
    }

    __syncthreads();   // final full barrier before the gather

    // ---- gather/store: 512 rows, 2 per thread, float4 each (write-exact) ----
    {
        const int r0 = tid;
        const int r1 = tid + 256;
        float4 o0, o1;
        o0.x = lout[r0 * 5 + 0]; o0.y = lout[r0 * 5 + 1];
        o0.z = lout[r0 * 5 + 2]; o0.w = lout[r0 * 5 + 3];
        o1.x = lout[r1 * 5 + 0]; o1.y = lout[r1 * 5 + 1];
        o1.z = lout[r1 * 5 + 2]; o1.w = lout[r1 * 5 + 3];
        *(float4*)(out + (size_t)(band + r0) * 128 + qt * 4) = o0;
        *(float4*)(out + (size_t)(band + r1) * 128 + qt * 4) = o1;
    }
}

extern "C" void kernel_launch(void* const* d_in, const int* in_sizes, int n_in,
                              void* d_out, int out_size, void* d_ws, size_t ws_size,
                              hipStream_t stream) {
    const float* x     = (const float*)d_in[0];
    const float* W1    = (const float*)d_in[1];
    const float* b1    = (const float*)d_in[2];
    const float* gamma = (const float*)d_in[3];
    const float* beta  = (const float*)d_in[4];
    const float* W2    = (const float*)d_in[5];
    const float* b2    = (const float*)d_in[6];
    float* out = (float*)d_out;

    dim3 grid(32, 32);   // (512-row bands, q-tiles of 4)
    divenc_mfma<<<grid, 256, 0, stream>>>(x, W1, b1, gamma, beta, W2, b2, out);
}

// Round 24
// 27.590 us; speedup vs baseline: 1.3063x; 1.0070x over previous
//
#include <hip/hip_runtime.h>

// DivEncLayer via MFMA — FINAL: r17 configuration (best measured, 27.68us).
// Per (b,q): h = elu(x[b,q*8:+8]@W1[q] + b1[q]); LN(h); out = h@W2[q]+b2[q].
// B=16384, Q=128, S=8, U=32.
//
// Structure (evolution over 23 rounds, survivors only):
//  - One v_mfma_f32_32x32x16_bf16 per 32-row tile; packed hi/lo A-frag:
//    lanes<32 = bf16(W1^T) (k<8), lanes>=32 = bf16(W1-whi) (k>=8); B dups
//    each row across lane halves -> D = (whi+wlo)*x_bf16 + b1 (C-in, fp32).
//    [r6: folded the 3-MFMA split into 1 MFMA]
//  - LN+Dense2 folded: out = rsqrt(var+eps)*(dot(e,g2) - mu*G) + C,
//    g2=gamma*W2, G=sum g2, C=sum(beta*W2)+b2. [r0]
//  - Block-cooperative coalesced staging: 8 thr cover one 128B x-row
//    (float4), cvt to bf16, LDS rows padded to 80B (0 bank conflicts).
//    [r11: +1.2us — per-lane strided loads were the front-end killer]
//  - 3-deep panel ring, loads issued 2 iters ahead, barriers =
//    s_waitcnt lgkmcnt(0) + s_barrier ONLY (no vmcnt drain: global loads
//    stay in flight across barriers). [r17: +1.0us]
//  - Results staged in padded LDS (stride 5); single batched gather ->
//    one float4 store per output row (WRITE_SIZE exact ~8.5MB). [r2]
// Refuted (null or negative, r7-r23): more blocks, more ILP chains,
// zero-barrier loops, depth-2 reg prefetch, global_load_lds depth-4 +
// counted vmcnt, producer/consumer wave, LDS-deferred epilogue, packed-f32
// math, merged-half finish, wave-private panels, start stagger.
//
// v_mfma_f32_32x32x16_bf16 mapping (HW-validated r2-r11):
//   A: lane l, reg j -> A[l&31][j+8*(l>>5)]  B: lane l, reg j -> B[j+8*(l>>5)][l&31]
//   D: lane l, reg r -> row u=(r&3)+8*(r>>2)+4*(l>>5), col b=l&31
// Block = 4 waves = q-tile (wave w owns q=qt*4+w); 8 iters x 64 rows =
// 512-row band; grid (32,32) = 1024 blocks.

typedef __attribute__((ext_vector_type(8))) short short8;    // 8 bf16
typedef __attribute__((ext_vector_type(16))) float f32x16;

#define XS_STRIDE 40   // shorts per staged row (80 B): b128-aligned, 0-conflict

__device__ __forceinline__ short fbits(__bf16 b) { return __builtin_bit_cast(short, b); }

__device__ __forceinline__ float elu1(float v) {
    return v > 0.f ? v : __expf(v) - 1.f;
}

__device__ __forceinline__ short4 cvt4(float4 v) {
    short4 r;
    r.x = fbits((__bf16)v.x); r.y = fbits((__bf16)v.y);
    r.z = fbits((__bf16)v.z); r.w = fbits((__bf16)v.w);
    return r;
}

// barrier WITHOUT vmcnt drain: DS visibility only, global loads stay in flight
__device__ __forceinline__ void barrier_ds_only() {
    asm volatile("s_waitcnt lgkmcnt(0)" ::: "memory");
    __builtin_amdgcn_s_barrier();
}

__global__ __launch_bounds__(256, 4) void divenc_mfma(
    const float* __restrict__ x,      // (16384, 1024)
    const float* __restrict__ W1,     // (128, 8, 32)
    const float* __restrict__ b1,     // (128, 32)
    const float* __restrict__ gamma,  // (128, 32)
    const float* __restrict__ beta,   // (128, 32)
    const float* __restrict__ W2,     // (128, 32)
    const float* __restrict__ b2,     // (128,)
    float* __restrict__ out)          // (16384, 128)
{
    __shared__ short xs[3][64 * XS_STRIDE];   // 3-deep staged bf16 panels (15 KB)
    __shared__ float lout[512 * 5];           // results, padded stride 5 (10 KB)

    const int tid  = threadIdx.x;
    const int w    = tid >> 6;
    const int ln   = tid & 63;
    const int u    = ln & 31;
    const int half = ln >> 5;
    const int qt   = blockIdx.y;      // 0..31
    const int q    = qt * 4 + w;
    const int bx   = blockIdx.x;      // 0..31; band = rows bx*512..+511
    const int band = bx * 512;

    // staging role: 8 threads cover one 128B row; thread t does rows t>>3, +32
    const int srow0 = tid >> 3;
    const int srow1 = srow0 + 32;
    const int schk  = tid & 7;
    const float* xpan = x + qt * 32 + schk * 4;

    // ---- A-frag: lanes<32 = whi (k=0..7), lanes>=32 = wlo (k=8..15) ----
    short8 wfrag;
    #pragma unroll
    for (int j = 0; j < 8; ++j) {
        float f  = W1[q * 256 + j * 32 + u];
        __bf16 h = (__bf16)f;
        wfrag[j] = half ? fbits((__bf16)(f - (float)h)) : fbits(h);
    }

    // ---- params: biasr (MFMA C-in) + g2r in regs, vector loads ----
    f32x16 biasr, g2r;
    float G, C;
    {
        float gs = 0.f, cs = 0.f;
        #pragma unroll
        for (int c = 0; c < 4; ++c) {
            const int ub = q * 32 + 4 * half + 8 * c;
            float4 b1v = *(const float4*)&b1[ub];
            float4 gav = *(const float4*)&gamma[ub];
            float4 w2v = *(const float4*)&W2[ub];
            float4 bev = *(const float4*)&beta[ub];
            #pragma unroll
            for (int j = 0; j < 4; ++j) {
                float g2 = ((const float*)&gav)[j] * ((const float*)&w2v)[j];
                biasr[4 * c + j] = ((const float*)&b1v)[j];
                g2r[4 * c + j]   = g2;
                gs += g2;
                cs += ((const float*)&bev)[j] * ((const float*)&w2v)[j];
            }
        }
        gs += __shfl_xor(gs, 32);   // halves hold complementary u-sets
        cs += __shfl_xor(cs, 32);
        G = gs;
        C = cs + b2[q];
    }

    // ---- prologue: stage panel 0; issue panel 1's loads (stay in flight) ----
    {
        float4 g0 = *(const float4*)(xpan + (size_t)(band + srow0) * 1024);
        float4 g1 = *(const float4*)(xpan + (size_t)(band + srow1) * 1024);
        *(short4*)&xs[0][srow0 * XS_STRIDE + schk * 4] = cvt4(g0);
        *(short4*)&xs[0][srow1 * XS_STRIDE + schk * 4] = cvt4(g1);
    }
    float4 p0 = *(const float4*)(xpan + (size_t)(band + 64 + srow0) * 1024);
    float4 p1 = *(const float4*)(xpan + (size_t)(band + 64 + srow1) * 1024);
    barrier_ds_only();

    #pragma unroll 1
    for (int it = 0; it < 8; ++it) {
        const int cur = it % 3;
        const int nxt = (it + 1) % 3;
        const int b0  = it * 64;        // row offset within band

        // issue loads for panel it+2 (2 iterations ahead; stay in flight)
        float4 f0, f1;
        if (it < 6) {
            f0 = *(const float4*)(xpan + (size_t)(band + b0 + 128 + srow0) * 1024);
            f1 = *(const float4*)(xpan + (size_t)(band + b0 + 128 + srow1) * 1024);
        }

        // ---- compute on panel cur ----
        short8 xa = *(const short8*)&xs[cur][u * XS_STRIDE + w * 8];
        short8 xb = *(const short8*)&xs[cur][(u + 32) * XS_STRIDE + w * 8];

        f32x16 accA = __builtin_amdgcn_mfma_f32_32x32x16_bf16(wfrag, xa, biasr, 0, 0, 0);
        f32x16 accB = __builtin_amdgcn_mfma_f32_32x32x16_bf16(wfrag, xb, biasr, 0, 0, 0);

        {
            float sum = 0.f, ss = 0.f, dot = 0.f;
            #pragma unroll
            for (int r = 0; r < 16; ++r) {
                float e = elu1(accA[r]);
                sum += e;
                ss  = fmaf(e, e, ss);
                dot = fmaf(e, g2r[r], dot);
            }
            sum += __shfl_xor(sum, 32);
            ss  += __shfl_xor(ss, 32);
            dot += __shfl_xor(dot, 32);
            float mu  = sum * 0.03125f;
            float var = fmaf(-mu, mu, ss * 0.03125f);
            float inv = rsqrtf(var + 1e-3f);
            float res = fmaf(inv, fmaf(-mu, G, dot), C);
            if (half == 0) lout[(b0 + u) * 5 + w] = res;
        }
        {
            float sum = 0.f, ss = 0.f, dot = 0.f;
            #pragma unroll
            for (int r = 0; r < 16; ++r) {
                float e = elu1(accB[r]);
                sum += e;
                ss  = fmaf(e, e, ss);
                dot = fmaf(e, g2r[r], dot);
            }
            sum += __shfl_xor(sum, 32);
            ss  += __shfl_xor(ss, 32);
            dot += __shfl_xor(dot, 32);
            float mu  = sum * 0.03125f;
            float var = fmaf(-mu, mu, ss * 0.03125f);
            float inv = rsqrtf(var + 1e-3f);
            float res = fmaf(inv, fmaf(-mu, G, dot), C);
            if (half == 0) lout[(b0 + 32 + u) * 5 + w] = res;
        }

        // ---- write panel it+1 from pending regs (vmcnt counted, not drained) ----
        if (it < 7) {
            *(short4*)&xs[nxt][srow0 * XS_STRIDE + schk * 4] = cvt4(p0);
            *(short4*)&xs[nxt][srow1 * XS_STRIDE + schk * 4] = cvt4(p1);
            barrier_ds_only();   // DS visibility only; vmcnt NOT drained
        }

        p0 = f0;
        p1 = f1;
    }

    __syncthreads();   // final full barrier before the gather

    // ---- gather/store: 512 rows, 2 per thread, float4 each (write-exact) ----
    {
        const int r0 = tid;
        const int r1 = tid + 256;
        float4 o0, o1;
        o0.x = lout[r0 * 5 + 0]; o0.y = lout[r0 * 5 + 1];
        o0.z = lout[r0 * 5 + 2]; o0.w = lout[r0 * 5 + 3];
        o1.x = lout[r1 * 5 + 0]; o1.y = lout[r1 * 5 + 1];
        o1.z = lout[r1 * 5 + 2]; o1.w = lout[r1 * 5 + 3];
        *(float4*)(out + (size_t)(band + r0) * 128 + qt * 4) = o0;
        *(float4*)(out + (size_t)(band + r1) * 128 + qt * 4) = o1;
    }
}

extern "C" void kernel_launch(void* const* d_in, const int* in_sizes, int n_in,
                              void* d_out, int out_size, void* d_ws, size_t ws_size,
                              hipStream_t stream) {
    const float* x     = (const float*)d_in[0];
    const float* W1    = (const float*)d_in[1];
    const float* b1    = (const float*)d_in[2];
    const float* gamma = (const float*)d_in[3];
    const float* beta  = (const float*)d_in[4];
    const float* W2    = (const float*)d_in[5];
    const float* b2    = (const float*)d_in[6];
    float* out = (float*)d_out;

    dim3 grid(32, 32);   // (512-row bands, q-tiles of 4)
    divenc_mfma<<<grid, 256, 0, stream>>>(x, W1, b1, gamma, beta, W2, b2, out);
}